// Round 5
// baseline (140.053 us; speedup 1.0000x reference)
//
#include <hip/hip_runtime.h>
#include <math.h>

// B=16, C_IN=256, C_OUT=256, H=W=64, K=3, NK=2
// weights: [2][256][256][3][3]; bank stride 589824 floats; per-o stride 2304.
//
// Pipeline:
//  1. scale_kernel: per (b,o) demod scale -> ws[scale]
//  2. wprep: combined+modulated+demod weights -> bf16 wq, LDS-image layout
//     per (b,ot4,c16): [p=20][ol=64][e=8], p = io*10 + j (j=9 zero dummy tap).
//  3. xprep: x -> bf16 xq [b][c16][rowp 66][colp 66][i 16], halo zeros baked.
//  4. conv_mfma: implicit GEMM via mfma_f32_16x16x32_bf16. Block = 256 thr
//     (4 waves) = 64 o x 4 rows x 64 px; grid 1024; 3 blocks/CU (LDS 44.8 KB).
//     x double-buffered (reg-staged linear copy + XOR bank swizzle),
//     weights single-buffered (reg-staged, write-late after barrier).
//  5. norm_kernel: channel RMSNorm * gamma * 16 + SiLU in place.

typedef __attribute__((ext_vector_type(8))) short short8;
typedef __attribute__((ext_vector_type(4))) float f32x4;

static __device__ __forceinline__ unsigned short f2bf(float v) {
  union { float f; unsigned u; } u;
  u.f = v;
  unsigned r = u.u + 0x7FFF + ((u.u >> 16) & 1);  // RNE
  return (unsigned short)(r >> 16);
}

// ---------------------------------------------------------------------------
// Kernel 1: per-(b,o) demodulation scale
// ---------------------------------------------------------------------------
__global__ __launch_bounds__(256) void scale_kernel(
    const float* __restrict__ mod, const float* __restrict__ kmod,
    const float* __restrict__ weights, float* __restrict__ scale) {
  int bo = blockIdx.x;
  int b = bo >> 8, o = bo & 255;

  float k0 = kmod[b * 2 + 0], k1 = kmod[b * 2 + 1];
  float mx = fmaxf(k0, k1);
  float e0 = expf(k0 - mx), e1 = expf(k1 - mx);
  float ai = 1.0f / (e0 + e1);
  float a0 = e0 * ai, a1 = e1 * ai;

  int t = threadIdx.x;
  const float* w0 = weights + (size_t)o * 2304;
  const float* w1 = w0 + 589824;

  float s = 0.0f;
#pragma unroll
  for (int r = 0; r < 9; r++) {
    int idx = t + r * 256;
    int i = idx / 9;
    float wv = a0 * w0[idx] + a1 * w1[idx];
    wv *= (mod[b * 256 + i] + 1.0f);
    s += wv * wv;
  }
#pragma unroll
  for (int off = 32; off > 0; off >>= 1) s += __shfl_down(s, off);

  __shared__ float red[4];
  if ((t & 63) == 0) red[t >> 6] = s;
  __syncthreads();
  if (t == 0) {
    float tot = red[0] + red[1] + red[2] + red[3];
    scale[bo] = rsqrtf(fmaxf(tot, 1e-8f));
  }
}

// ---------------------------------------------------------------------------
// Kernel 2: weight prep -> bf16 LDS-image in wq.
// Grid 1024: blk = (b*4 + ot4)*16 + c. Chunk = [p20][ol64][e8] = 20 KB.
// ---------------------------------------------------------------------------
__global__ __launch_bounds__(256) void wprep(
    const float* __restrict__ mod, const float* __restrict__ kmod,
    const float* __restrict__ weights, const float* __restrict__ scale,
    unsigned short* __restrict__ wq) {
  __shared__ __align__(16) unsigned short buf[10240];
  int blk = blockIdx.x;  // (b*4 + ot)*16 + c
  int b = blk >> 6, ot = (blk >> 4) & 3, c = blk & 15;
  int t = threadIdx.x;

  float k0 = kmod[b * 2 + 0], k1 = kmod[b * 2 + 1];
  float mx = fmaxf(k0, k1);
  float e0 = expf(k0 - mx), e1 = expf(k1 - mx);
  float ai = 1.0f / (e0 + e1);
  float a0 = e0 * ai, a1 = e1 * ai;

  // zero the two dummy-tap rows (p=9, p=19): 1024 elems
#pragma unroll
  for (int k = 0; k < 4; ++k) {
    int e = t + k * 256;
    int half = e >> 9;
    buf[(half * 10 + 9) * 512 + (e & 511)] = 0;
  }

  int ol = t >> 2, q = t & 3;
  int o = ot * 64 + ol;
  float sc = scale[b * 256 + o];
#pragma unroll
  for (int io = 0; io < 2; ++io) {
#pragma unroll
    for (int e2 = 0; e2 < 2; ++e2) {
      int e = q * 2 + e2;
      int i = c * 16 + io * 8 + e;
      float f = (mod[b * 256 + i] + 1.0f) * sc;
      const float* w0 = &weights[((size_t)o * 256 + i) * 9];
      const float* w1 = w0 + 589824;
#pragma unroll
      for (int j = 0; j < 9; ++j) {
        float v = (a0 * w0[j] + a1 * w1[j]) * f;
        buf[(io * 10 + j) * 512 + ol * 8 + e] = f2bf(v);
      }
    }
  }
  __syncthreads();
  size_t base = (size_t)blk * 10240;
#pragma unroll
  for (int k = 0; k < 5; ++k) {
    int idx = t + k * 256;
    *(short8*)(wq + base + (size_t)idx * 8) = *(const short8*)&buf[idx * 8];
  }
}

// ---------------------------------------------------------------------------
// Kernel 3: x prep -> bf16 xq [b][c16][rowp 66][colp 66][i 16], halo zeroed.
// ---------------------------------------------------------------------------
__global__ __launch_bounds__(256) void xprep(
    const float* __restrict__ x, unsigned short* __restrict__ xq) {
  int blk = blockIdx.x;  // (b*16 + c)*66 + rowp
  int rowp = blk % 66;
  int bc = blk / 66;
  int b = bc >> 4, c = bc & 15;
  int t = threadIdx.x;
  size_t obase = (size_t)blk * 1056;

  if (rowp == 0 || rowp == 65) {
    for (int idx = t; idx < 1056; idx += 256) xq[obase + idx] = 0;
    return;
  }
  __shared__ __align__(16) unsigned short xs2[1056];
  int row = rowp - 1;
  for (int idx = t; idx < 1056; idx += 256) xs2[idx] = 0;
  __syncthreads();
#pragma unroll
  for (int k = 0; k < 4; ++k) {
    int idx = t + k * 256;  // 0..1023
    int il = idx >> 6, col = idx & 63;
    float v = x[(((size_t)b * 256 + c * 16 + il) * 64 + row) * 64 + col];
    xs2[(col + 1) * 16 + il] = f2bf(v);
  }
  __syncthreads();
  if (t < 132) *(short8*)(xq + obase + (size_t)t * 8) = *(const short8*)&xs2[t * 8];
}

// ---------------------------------------------------------------------------
// Kernel 4: implicit-GEMM conv. 3 blocks/CU. x dbuf + XOR swizzle; w single-buf
// reg-staged write-late. Grid 1024; block 256 thr (4 waves), wave = out row.
// ---------------------------------------------------------------------------
__global__ __launch_bounds__(256, 3) void conv_mfma(
    const unsigned short* __restrict__ xq, const unsigned short* __restrict__ wq,
    float* __restrict__ out) {
  __shared__ __align__(16) unsigned short wsm[10240];     // [p20][ol64][e8] 20 KB
  __shared__ __align__(16) unsigned short xsm[2][6336];   // [rl6][colp66][i16] 12.4 KB x2

  int bid = blockIdx.x;
  // XCD clustering: xcd = bid&7 owns b = {2*xcd, 2*xcd+1}
  int xcd = bid & 7;
  int kk = bid >> 3;  // 0..127
  int b = xcd * 2 + (kk >> 6);
  int rem = kk & 63;
  int ot = rem >> 4;  // 64-o quarter
  int rt = rem & 15;  // 4-row tile
  int r0 = rt * 4;

  int t = threadIdx.x;
  int w = t >> 6, lane = t & 63;
  int g = (t >> 4) & 3, lm = t & 15;

  // per-s LDS read offsets (bytes), loop-invariant across c.
  // B addr: ((w+kh)*66 + colp)*32 + io*16, colp = nf*16 + lm + kw (nf adds 512B,
  // which does not touch bit7 -> swizzle constant across nf).
  int baddr_[5], aaddr_[5];
#pragma unroll
  for (int s = 0; s < 5; ++s) {
    int p = 4 * s + g;
    int io = (p >= 10) ? 1 : 0;
    int j = p - 10 * io;
    int jd3, jm3;
    if (j == 9) { jd3 = 0; jm3 = 0; }  // dummy tap: weights zero
    else { jd3 = (j >= 3) + (j >= 6); jm3 = j - 3 * jd3; }
    int ba = ((w + jd3) * 66 + lm + jm3) * 32 + io * 16;
    ba ^= ((ba >> 7) & 1) << 4;  // bank swizzle (must match XWRITE)
    baddr_[s] = ba;
    aaddr_[s] = p * 1024 + lm * 16;
  }

  f32x4 acc[4][4];
#pragma unroll
  for (int mf = 0; mf < 4; ++mf)
#pragma unroll
    for (int nf = 0; nf < 4; ++nf) acc[mf][nf] = (f32x4){0.f, 0.f, 0.f, 0.f};

  short8 xr0, xr1, xr2, xr3;
  short8 wr0, wr1, wr2, wr3, wr4;

  // x write offsets: linear slab idx*16B with XOR swizzle
  int xw0 = (t * 16) ^ (((t * 16 >> 7) & 1) << 4);
  int xw1 = ((t + 256) * 16) ^ ((((t + 256) * 16 >> 7) & 1) << 4);
  int xw2 = ((t + 512) * 16) ^ ((((t + 512) * 16 >> 7) & 1) << 4);
  int xw3 = ((t + 768) * 16) ^ ((((t + 768) * 16 >> 7) & 1) << 4);

#define XLOAD(cn)                                                              \
  {                                                                            \
    const unsigned short* xs_ =                                                \
        xq + (size_t)((b * 16 + (cn)) * 66 + r0) * 1056;                       \
    xr0 = *(const short8*)(xs_ + (size_t)t * 8);                               \
    xr1 = *(const short8*)(xs_ + (size_t)(t + 256) * 8);                       \
    xr2 = *(const short8*)(xs_ + (size_t)(t + 512) * 8);                       \
    if (t < 24) xr3 = *(const short8*)(xs_ + (size_t)(t + 768) * 8);           \
  }

#define WLOAD(cn)                                                              \
  {                                                                            \
    const unsigned short* ws_ =                                                \
        wq + ((size_t)(b * 4 + ot) * 16 + (cn)) * 10240 + t * 8;               \
    wr0 = *(const short8*)(ws_ + 0 * 2048);                                    \
    wr1 = *(const short8*)(ws_ + 1 * 2048);                                    \
    wr2 = *(const short8*)(ws_ + 2 * 2048);                                    \
    wr3 = *(const short8*)(ws_ + 3 * 2048);                                    \
    wr4 = *(const short8*)(ws_ + 4 * 2048);                                    \
  }

#define XWRITE(nb)                                                             \
  {                                                                            \
    char* xb_ = (char*)xsm[nb];                                                \
    *(short8*)(xb_ + xw0) = xr0;                                               \
    *(short8*)(xb_ + xw1) = xr1;                                               \
    *(short8*)(xb_ + xw2) = xr2;                                               \
    if (t < 24) *(short8*)(xb_ + xw3) = xr3;                                   \
  }

#define WWRITE()                                                               \
  {                                                                            \
    short8* wb_ = (short8*)wsm;                                                \
    wb_[t + 0 * 256] = wr0;                                                    \
    wb_[t + 1 * 256] = wr1;                                                    \
    wb_[t + 2 * 256] = wr2;                                                    \
    wb_[t + 3 * 256] = wr3;                                                    \
    wb_[t + 4 * 256] = wr4;                                                    \
  }

  // prologue: stage c=0
  XLOAD(0);
  WLOAD(0);
  XWRITE(0);
  WWRITE();
  __syncthreads();

  for (int c = 0; c < 16; ++c) {
    int cur = c & 1;
    if (c < 15) {
      XLOAD(c + 1);  // issue-early (separate BB -> stays before compute)
      WLOAD(c + 1);
    }
    // ---- compute on wsm + xsm[cur] ----
    {
      const char* wsb = (const char*)wsm;
      const char* xsb = (const char*)xsm[cur];
#pragma unroll
      for (int s = 0; s < 5; ++s) {
        short8 A[4];
#pragma unroll
        for (int mf = 0; mf < 4; ++mf)
          A[mf] = *(const short8*)(wsb + aaddr_[s] + mf * 256);
#pragma unroll
        for (int nf = 0; nf < 4; ++nf) {
          short8 Bf = *(const short8*)(xsb + baddr_[s] + nf * 512);
#pragma unroll
          for (int mf = 0; mf < 4; ++mf)
            acc[mf][nf] =
                __builtin_amdgcn_mfma_f32_16x16x32_bf16(A[mf], Bf, acc[mf][nf], 0, 0, 0);
        }
      }
    }
    __syncthreads();  // all waves done reading wsm/xsm[cur]
    if (c < 15) {
      XWRITE(cur ^ 1);  // write-late (vmcnt waits resolved long ago)
      WWRITE();
      __syncthreads();  // staged data visible for next iter
    }
  }

  // ---- epilogue: D col=lane&15 (px), row-in-frag=4*(lane>>4)+q (o) ----
  int row = r0 + w;
#pragma unroll
  for (int mf = 0; mf < 4; ++mf)
#pragma unroll
    for (int nf = 0; nf < 4; ++nf)
#pragma unroll
      for (int q = 0; q < 4; ++q) {
        int o = ot * 64 + mf * 16 + g * 4 + q;
        int col = nf * 16 + lm;
        out[(((size_t)b * 256 + o) * 64 + row) * 64 + col] = acc[mf][nf][q];
      }
#undef XLOAD
#undef WLOAD
#undef XWRITE
#undef WWRITE
}

// ---------------------------------------------------------------------------
// Kernel 5: channel RMSNorm * gamma * 16 + SiLU, in place.
// ---------------------------------------------------------------------------
__global__ __launch_bounds__(256) void norm_kernel(
    float* __restrict__ y, const float* __restrict__ gamma) {
  int blk = blockIdx.x;
  int b = blk >> 6, h = blk & 63;
  int t = threadIdx.x;
  int p = t & 63, og = t >> 6;

  size_t base = (((size_t)b * 256) * 64 + h) * 64 + p;
  float yv[64];
  float s = 0.0f;
#pragma unroll
  for (int k = 0; k < 64; k++) {
    yv[k] = y[base + (size_t)(og * 64 + k) * 4096];
    s = fmaf(yv[k], yv[k], s);
  }

  __shared__ float red[4][64];
  __shared__ float invs[64];
  red[og][p] = s;
  __syncthreads();
  if (og == 0) {
    float tot = red[0][p] + red[1][p] + red[2][p] + red[3][p];
    float nrm = sqrtf(tot);
    invs[p] = 16.0f / fmaxf(nrm, 1e-12f);
  }
  __syncthreads();
  float iv = invs[p];
#pragma unroll
  for (int k = 0; k < 64; k++) {
    int o = og * 64 + k;
    float v = yv[k] * iv * gamma[o];
    float sg = 1.0f / (1.0f + expf(-v));
    y[base + (size_t)o * 4096] = v * sg;
  }
}

extern "C" void kernel_launch(void* const* d_in, const int* in_sizes, int n_in,
                              void* d_out, int out_size, void* d_ws, size_t ws_size,
                              hipStream_t stream) {
  const float* x = (const float*)d_in[0];
  const float* mod = (const float*)d_in[1];
  const float* kmod = (const float*)d_in[2];
  const float* weights = (const float*)d_in[3];
  const float* gamma = (const float*)d_in[4];
  float* out = (float*)d_out;

  // ws layout: wq 20,971,520 B | scale 16,384 B | xq 35,684,352 B  (~56.7 MB)
  unsigned short* wq = (unsigned short*)d_ws;
  float* scale = (float*)((char*)d_ws + 20971520);
  unsigned short* xq = (unsigned short*)((char*)d_ws + 20987904);

  scale_kernel<<<16 * 256, 256, 0, stream>>>(mod, kmod, weights, scale);
  wprep<<<1024, 256, 0, stream>>>(mod, kmod, weights, scale, wq);
  xprep<<<16 * 16 * 66, 256, 0, stream>>>(x, xq);
  conv_mfma<<<1024, 256, 0, stream>>>(xq, wq, out);
  norm_kernel<<<16 * 64, 256, 0, stream>>>(out, gamma);
}